// Round 3
// baseline (15440.889 us; speedup 1.0000x reference)
//
#include <hip/hip_runtime.h>

#define B_ 64
#define T_ 256
#define H_ 1024
#define S_ 128
#define OBS_ 1024
#define ACT_ 32

typedef __attribute__((ext_vector_type(8))) short bf16x8;
typedef __attribute__((ext_vector_type(4))) float f32x4;

#define MFMA(a, b, c) __builtin_amdgcn_mfma_f32_16x16x32_bf16((a), (b), (c), 0, 0, 0)

__device__ __forceinline__ short f2bf(float f) {
    unsigned int u; __builtin_memcpy(&u, &f, 4);
    unsigned int r = (u + 0x7fffu + ((u >> 16) & 1u)) >> 16;
    return (short)r;
}
__device__ __forceinline__ bf16x8 ld8(const short* p) { return *(const bf16x8*)p; }
__device__ __forceinline__ bf16x8 cvt8(const float* p) {
    bf16x8 r;
#pragma unroll
    for (int i = 0; i < 8; ++i) r[i] = f2bf(p[i]);
    return r;
}
__device__ __forceinline__ float sigm(float x) { return 1.f / (1.f + __expf(-x)); }
__device__ __forceinline__ float tanh_f(float x) { return 1.f - 2.f / (__expf(2.f * x) + 1.f); }
__device__ __forceinline__ float splus(float x) { return (x > 20.f) ? x : log1pf(__expf(x)); }

// fp32 -> bf16 array conversion (vectorized by 4)
__global__ void f2bf_arr(const float* __restrict__ src, short* __restrict__ dst, int n4) {
    int i = blockIdx.x * blockDim.x + threadIdx.x;
    if (i < n4) {
        float4 v = ((const float4*)src)[i];
        short4 o;
        o.x = f2bf(v.x); o.y = f2bf(v.y); o.z = f2bf(v.z); o.w = f2bf(v.w);
        ((short4*)dst)[i] = o;
    }
}

// Zero the recurrent-state buffers (d_ws is poisoned 0xAA before every launch).
__global__ void init_ws(float* __restrict__ h_f32, short* __restrict__ h_bf,
                        short* __restrict__ z_bf) {
    int i = blockIdx.x * blockDim.x + threadIdx.x;  // grid 256x256 = 65536
    h_f32[i] = 0.f;
    h_bf[i] = 0;
    if (i < B_ * S_) z_bf[i] = 0;
}

// Phase 1: h_t = GRU(h_{t-1}, [z_{t-1}, a_{t-1}])
// grid: 64 blocks (16 h-cols each) x 256 threads (4 waves = 4 row-groups of 16)
__global__ __launch_bounds__(256) void step_h(
    const short* __restrict__ act_bf, const unsigned char* __restrict__ resets,
    const short* __restrict__ w_ih, const short* __restrict__ w_hh,
    const float* __restrict__ b_ih, const float* __restrict__ b_hh,
    const float* __restrict__ h_rd, float* __restrict__ h_wr,
    const short* __restrict__ hb_rd, short* __restrict__ hb_wr,
    const short* __restrict__ z_bf, float* __restrict__ out_h, int t) {
    const int rg = threadIdx.x >> 6;
    const int lane = threadIdx.x & 63;
    const int c = lane & 15, q = lane >> 4;
    const int j0 = blockIdx.x * 16;
    const int m0 = rg * 16;
    const int arow = m0 + c;     // A-fragment row (batch)
    const int n = j0 + c;        // B-fragment row / output column
    const bool mz = (t > 0) && (resets[arow] != 0);
    const bf16x8 zv = {0, 0, 0, 0, 0, 0, 0, 0};

    f32x4 aR = {0.f, 0.f, 0.f, 0.f};
    f32x4 aU = aR, aIN = aR, aHN = aR;

    // gi over z (K=128): x[:, :128] = z_{t-1} (masked by resets for t>0)
    {
        const short* wr = w_ih + (size_t)n * 160;
        const short* wu = w_ih + (size_t)(H_ + n) * 160;
        const short* wn = w_ih + (size_t)(2 * H_ + n) * 160;
        const short* za = z_bf + arow * S_;
#pragma unroll
        for (int kb = 0; kb < 4; ++kb) {
            const int k = kb * 32 + q * 8;
            bf16x8 a = mz ? zv : ld8(za + k);
            aR = MFMA(a, ld8(wr + k), aR);
            aU = MFMA(a, ld8(wu + k), aU);
            aIN = MFMA(a, ld8(wn + k), aIN);
        }
        // gi over prev_action (K=32); prev_act = 0 at t=0, NOT reset-masked
        if (t > 0) {
            const int k = q * 8;
            bf16x8 a = ld8(act_bf + (size_t)arow * (T_ * ACT_) + (size_t)(t - 1) * ACT_ + k);
            aR = MFMA(a, ld8(wr + 128 + k), aR);
            aU = MFMA(a, ld8(wu + 128 + k), aU);
            aIN = MFMA(a, ld8(wn + 128 + k), aIN);
        }
    }
    // gh over h (K=1024), h masked by resets for t>0
    {
        const short* wr = w_hh + (size_t)n * H_;
        const short* wu = w_hh + (size_t)(H_ + n) * H_;
        const short* wn = w_hh + (size_t)(2 * H_ + n) * H_;
        const short* ha = hb_rd + arow * H_;
#pragma unroll 8
        for (int kb = 0; kb < 32; ++kb) {
            const int k = kb * 32 + q * 8;
            bf16x8 a = mz ? zv : ld8(ha + k);
            aR = MFMA(a, ld8(wr + k), aR);
            aU = MFMA(a, ld8(wu + k), aU);
            aHN = MFMA(a, ld8(wn + k), aHN);
        }
    }
    const float biR = b_ih[n], bhR = b_hh[n];
    const float biU = b_ih[H_ + n], bhU = b_hh[H_ + n];
    const float biN = b_ih[2 * H_ + n], bhN = b_hh[2 * H_ + n];
#pragma unroll
    for (int e = 0; e < 4; ++e) {
        const int row = m0 + q * 4 + e;  // C/D layout: row = quad*4 + reg
        const float keep = ((t > 0) && (resets[row] != 0)) ? 0.f : 1.f;
        const float hp = h_rd[row * H_ + n] * keep;
        const float r = sigm(aR[e] + biR + bhR);
        const float u = sigm(aU[e] + biU + bhU);
        const float nn = tanh_f(aIN[e] + biN + r * (aHN[e] + bhN));
        const float hv = (1.f - u) * nn + u * hp;
        h_wr[row * H_ + n] = hv;
        hb_wr[row * H_ + n] = f2bf(hv);
        out_h[(size_t)row * (T_ * H_) + (size_t)t * H_ + n] = hv;  // h_seq [B,T,H] fp32
    }
}

// Phase 2: po_hidden = relu([h_t, obs_t] @ po_w1^T + po_b1)
// grid: 64 blocks x 256 threads
__global__ __launch_bounds__(256) void step_po1(
    const float* __restrict__ obs, const short* __restrict__ po_w1,
    const float* __restrict__ po_b1, const short* __restrict__ hb,
    short* __restrict__ poh, int t) {
    const int rg = threadIdx.x >> 6;
    const int lane = threadIdx.x & 63;
    const int c = lane & 15, q = lane >> 4;
    const int j0 = blockIdx.x * 16;
    const int m0 = rg * 16;
    const int arow = m0 + c;
    const int n = j0 + c;

    f32x4 acc = {0.f, 0.f, 0.f, 0.f};
    const short* w = po_w1 + (size_t)n * 2048;
    const short* ha = hb + arow * H_;
#pragma unroll 8
    for (int kb = 0; kb < 32; ++kb) {
        const int k = kb * 32 + q * 8;
        acc = MFMA(ld8(ha + k), ld8(w + k), acc);
    }
    const float* ob = obs + (size_t)arow * (T_ * OBS_) + (size_t)t * OBS_;
#pragma unroll 4
    for (int kb = 0; kb < 32; ++kb) {
        const int k = kb * 32 + q * 8;
        acc = MFMA(cvt8(ob + k), ld8(w + 1024 + k), acc);
    }
    const float bias = po_b1[n];
#pragma unroll
    for (int e = 0; e < 4; ++e) {
        const int row = m0 + q * 4 + e;
        poh[row * 1024 + n] = f2bf(fmaxf(acc[e] + bias, 0.f));
    }
}

// Phase 3: qp = po_hidden @ po_w2^T + po_b2 ; split; z = qm + qs*noise
// grid: 8 blocks x 256 threads
__global__ __launch_bounds__(256) void step_po2(
    const float* __restrict__ noise, const short* __restrict__ po_w2,
    const float* __restrict__ po_b2, const short* __restrict__ poh,
    short* __restrict__ z_bf, float* __restrict__ out_qm, float* __restrict__ out_qs,
    float* __restrict__ out_z, int t) {
    const int rg = threadIdx.x >> 6;
    const int lane = threadIdx.x & 63;
    const int c = lane & 15, q = lane >> 4;
    const int j0 = blockIdx.x * 16;
    const int m0 = rg * 16;
    const int arow = m0 + c;
    const int s = j0 + c;

    f32x4 aM = {0.f, 0.f, 0.f, 0.f};
    f32x4 aS = aM;
    const short* wm = po_w2 + (size_t)s * 1024;
    const short* ws2 = po_w2 + (size_t)(S_ + s) * 1024;
    const short* pa = poh + arow * 1024;
#pragma unroll 8
    for (int kb = 0; kb < 32; ++kb) {
        const int k = kb * 32 + q * 8;
        bf16x8 a = ld8(pa + k);
        aM = MFMA(a, ld8(wm + k), aM);
        aS = MFMA(a, ld8(ws2 + k), aS);
    }
    const float bM = po_b2[s], bS = po_b2[S_ + s];
#pragma unroll
    for (int e = 0; e < 4; ++e) {
        const int row = m0 + q * 4 + e;
        const float qm = aM[e] + bM;
        const float qs = splus(aS[e] + bS) + 1e-6f;
        const float nv = noise[(size_t)row * (T_ * S_) + (size_t)t * S_ + s];
        const float zz = qm + qs * nv;
        out_qm[(size_t)row * (S_ * T_) + (size_t)s * T_ + t] = qm;  // [B,S,T]
        out_qs[(size_t)row * (S_ * T_) + (size_t)s * T_ + t] = qs;
        out_z[(size_t)row * (T_ * S_) + (size_t)t * S_ + s] = zz;   // z_seq [B,T,S]
        z_bf[row * S_ + s] = f2bf(zz);
    }
}

// Batched prior MLP over all B*T rows (off critical path): pm, ps
// grid: 256 blocks (64 rows each) x 256 threads
__global__ __launch_bounds__(256) void prior_mlp(
    const float* __restrict__ hseq, const short* __restrict__ pr_w1,
    const float* __restrict__ pr_b1, const short* __restrict__ pr_w2,
    const float* __restrict__ pr_b2, float* __restrict__ out_pm,
    float* __restrict__ out_ps) {
    __shared__ __align__(16) short hid[64][512];  // exactly 64 KiB
    const int w = threadIdx.x >> 6;
    const int lane = threadIdx.x & 63;
    const int c = lane & 15, q = lane >> 4;
    const long rb0 = (long)blockIdx.x * 64;

    // stage 1: hidden = relu(h @ pr_w1^T + pr_b1); A-fragments cached in regs
    bf16x8 afr[32];
    const float* ap = hseq + (rb0 + w * 16 + c) * 1024;
#pragma unroll
    for (int kb = 0; kb < 32; ++kb) afr[kb] = cvt8(ap + kb * 32 + q * 8);
    for (int jt = 0; jt < 32; ++jt) {
        f32x4 acc = {0.f, 0.f, 0.f, 0.f};
        const short* wgt = pr_w1 + (size_t)(jt * 16 + c) * 1024;
#pragma unroll 8
        for (int kb = 0; kb < 32; ++kb) {
            acc = MFMA(afr[kb], ld8(wgt + kb * 32 + q * 8), acc);
        }
        const float bias = pr_b1[jt * 16 + c];
#pragma unroll
        for (int e = 0; e < 4; ++e) {
            hid[w * 16 + q * 4 + e][jt * 16 + c] = f2bf(fmaxf(acc[e] + bias, 0.f));
        }
    }
    __syncthreads();
    // stage 2: pp = hidden @ pr_w2^T + pr_b2
    bf16x8 afr2[16];
#pragma unroll
    for (int kb = 0; kb < 16; ++kb) afr2[kb] = *(const bf16x8*)(&hid[w * 16 + c][kb * 32 + q * 8]);
    for (int jt = 0; jt < 16; ++jt) {
        f32x4 acc = {0.f, 0.f, 0.f, 0.f};
        const short* wgt = pr_w2 + (size_t)(jt * 16 + c) * 512;
#pragma unroll 8
        for (int kb = 0; kb < 16; ++kb) {
            acc = MFMA(afr2[kb], ld8(wgt + kb * 32 + q * 8), acc);
        }
        const int col = jt * 16 + c;
#pragma unroll
        for (int e = 0; e < 4; ++e) {
            const long rgidx = rb0 + w * 16 + q * 4 + e;
            const int b_ = (int)(rgidx >> 8), t_ = (int)(rgidx & 255);
            if (col < S_) {
                out_pm[(size_t)b_ * (S_ * T_) + (size_t)col * T_ + t_] = acc[e] + pr_b2[col];
            } else {
                out_ps[(size_t)b_ * (S_ * T_) + (size_t)(col - S_) * T_ + t_] =
                    splus(acc[e] + pr_b2[col]) + 1e-6f;
            }
        }
    }
}

extern "C" void kernel_launch(void* const* d_in, const int* in_sizes, int n_in,
                              void* d_out, int out_size, void* d_ws, size_t ws_size,
                              hipStream_t stream) {
    const float* obs = (const float*)d_in[0];
    const float* action = (const float*)d_in[1];
    const unsigned char* resets = (const unsigned char*)d_in[2];
    const float* noise = (const float*)d_in[3];
    const float* w_ih = (const float*)d_in[4];
    const float* w_hh = (const float*)d_in[5];
    const float* b_ih = (const float*)d_in[6];
    const float* b_hh = (const float*)d_in[7];
    const float* pr_w1 = (const float*)d_in[8];
    const float* pr_b1 = (const float*)d_in[9];
    const float* pr_w2 = (const float*)d_in[10];
    const float* pr_b2 = (const float*)d_in[11];
    const float* po_w1 = (const float*)d_in[12];
    const float* po_b1 = (const float*)d_in[13];
    const float* po_w2 = (const float*)d_in[14];
    const float* po_b2 = (const float*)d_in[15];

    float* out = (float*)d_out;
    const size_t BST = (size_t)B_ * S_ * T_;  // 2097152
    float* out_pm = out;
    float* out_ps = out + BST;
    float* out_qm = out + 2 * BST;
    float* out_qs = out + 3 * BST;
    float* out_h = out + 4 * BST;                        // [B,T,H]
    float* out_z = out + 4 * BST + (size_t)B_ * T_ * H_; // [B,T,S]

    char* w = (char*)d_ws;
    float* h_f32 = (float*)w;                           // [2][64*1024]
    short* h_bf = (short*)(w + 524288);                 // [2][64*1024]
    short* z_bf = (short*)(w + 786432);                 // [64*128]
    short* poh = (short*)(w + 802816);                  // [64*1024]
    short* act_bf = (short*)(w + 933888);               // [64*256*32]
    short* w_ih_bf = (short*)(w + 1982464);             // [3072*160]
    short* w_hh_bf = (short*)(w + 2965504);             // [3072*1024]
    short* po_w1_bf = (short*)(w + 9256960);            // [1024*2048]
    short* po_w2_bf = (short*)(w + 13451264);           // [256*1024]
    short* pr_w1_bf = (short*)(w + 13975552);           // [512*1024]
    short* pr_w2_bf = (short*)(w + 15024128);           // [256*512]

    auto cvt = [&](const float* s, short* d, int n) {
        int n4 = n / 4;
        f2bf_arr<<<dim3((n4 + 255) / 256), 256, 0, stream>>>(s, d, n4);
    };
    cvt(action, act_bf, B_ * T_ * ACT_);
    cvt(w_ih, w_ih_bf, 3 * H_ * (S_ + ACT_));
    cvt(w_hh, w_hh_bf, 3 * H_ * H_);
    cvt(po_w1, po_w1_bf, 1024 * 2048);
    cvt(po_w2, po_w2_bf, 256 * 1024);
    cvt(pr_w1, pr_w1_bf, 512 * 1024);
    cvt(pr_w2, pr_w2_bf, 256 * 512);
    init_ws<<<dim3(256), 256, 0, stream>>>(h_f32, h_bf, z_bf);

    for (int t = 0; t < T_; ++t) {
        const int rd = t & 1, wr2 = (t + 1) & 1;
        step_h<<<dim3(64), 256, 0, stream>>>(
            act_bf, resets, w_ih_bf, w_hh_bf, b_ih, b_hh,
            h_f32 + rd * 65536, h_f32 + wr2 * 65536,
            h_bf + rd * 65536, h_bf + wr2 * 65536,
            z_bf, out_h, t);
        step_po1<<<dim3(64), 256, 0, stream>>>(obs, po_w1_bf, po_b1, h_bf + wr2 * 65536, poh, t);
        step_po2<<<dim3(8), 256, 0, stream>>>(noise, po_w2_bf, po_b2, poh, z_bf,
                                              out_qm, out_qs, out_z, t);
    }
    prior_mlp<<<dim3(256), 256, 0, stream>>>(out_h, pr_w1_bf, pr_b1, pr_w2_bf, pr_b2,
                                             out_pm, out_ps);
}

// Round 4
// 14548.283 us; speedup vs baseline: 1.0614x; 1.0614x over previous
//
#include <hip/hip_runtime.h>

#define B_ 64
#define T_ 256
#define H_ 1024
#define S_ 128
#define OBS_ 1024
#define ACT_ 32

typedef __attribute__((ext_vector_type(8))) short bf16x8;
typedef __attribute__((ext_vector_type(4))) float f32x4;

#define MFMA(a, b, c) __builtin_amdgcn_mfma_f32_16x16x32_bf16((a), (b), (c), 0, 0, 0)

__device__ __forceinline__ float bf2f(short s) {
    unsigned int u = ((unsigned int)(unsigned short)s) << 16;
    float f; __builtin_memcpy(&f, &u, 4); return f;
}
__device__ __forceinline__ short f2bf(float f) {
    unsigned int u; __builtin_memcpy(&u, &f, 4);
    unsigned int r = (u + 0x7fffu + ((u >> 16) & 1u)) >> 16;
    return (short)r;
}
__device__ __forceinline__ bf16x8 ld8(const short* p) { return *(const bf16x8*)p; }
__device__ __forceinline__ bf16x8 cvt8(const float* p) {
    bf16x8 r;
#pragma unroll
    for (int i = 0; i < 8; ++i) r[i] = f2bf(p[i]);
    return r;
}
// agent-scope (LLC-coherent) 16B load as two 8B atomics — cross-XCD safe
__device__ __forceinline__ bf16x8 lda8(const short* p) {
    const unsigned long long* q8 = (const unsigned long long*)p;
    union { unsigned long long q[2]; bf16x8 v; } u;
    u.q[0] = __hip_atomic_load(q8, __ATOMIC_RELAXED, __HIP_MEMORY_SCOPE_AGENT);
    u.q[1] = __hip_atomic_load(q8 + 1, __ATOMIC_RELAXED, __HIP_MEMORY_SCOPE_AGENT);
    return u.v;
}
__device__ __forceinline__ void sta8(short* p, unsigned long long v) {
    __hip_atomic_store((unsigned long long*)p, v, __ATOMIC_RELAXED, __HIP_MEMORY_SCOPE_AGENT);
}
__device__ __forceinline__ unsigned long long pk4(float4 v) {
    return (unsigned long long)(unsigned short)f2bf(v.x)
         | ((unsigned long long)(unsigned short)f2bf(v.y) << 16)
         | ((unsigned long long)(unsigned short)f2bf(v.z) << 32)
         | ((unsigned long long)(unsigned short)f2bf(v.w) << 48);
}
__device__ __forceinline__ float sigm(float x) { return 1.f / (1.f + __expf(-x)); }
__device__ __forceinline__ float tanh_f(float x) { return 1.f - 2.f / (__expf(2.f * x) + 1.f); }
__device__ __forceinline__ float splus(float x) { return (x > 20.f) ? x : log1pf(__expf(x)); }

// grid barrier: flag-array arrive + 64-lane gather poll. Relies on __syncthreads'
// vmcnt(0) drain (agent stores are write-through to LLC) for release semantics.
__device__ __forceinline__ void gridbar(int* flags, int e) {
    __syncthreads();
    if (threadIdx.x == 0)
        __hip_atomic_store(&flags[blockIdx.x * 16], e, __ATOMIC_RELAXED, __HIP_MEMORY_SCOPE_AGENT);
    if (threadIdx.x < 64) {
        while (__hip_atomic_load(&flags[threadIdx.x * 16], __ATOMIC_RELAXED,
                                 __HIP_MEMORY_SCOPE_AGENT) < e)
            __builtin_amdgcn_s_sleep(1);
    }
    __syncthreads();
}

__global__ void f2bf_arr(const float* __restrict__ src, short* __restrict__ dst, int n4) {
    int i = blockIdx.x * blockDim.x + threadIdx.x;
    if (i < n4) {
        float4 v = ((const float4*)src)[i];
        short4 o;
        o.x = f2bf(v.x); o.y = f2bf(v.y); o.z = f2bf(v.z); o.w = f2bf(v.w);
        ((short4*)dst)[i] = o;
    }
}

// obs_part[t][b][n] = obs[b,t,:] @ po_w1[:,1024:]^T + po_b1  (bf16, off critical path)
// grid: 256 blocks (one per t) x 256 threads
__global__ __launch_bounds__(256) void obs_gemm(
    const float* __restrict__ obs, const short* __restrict__ po_w1,
    const float* __restrict__ po_b1, short* __restrict__ part) {
    const int t = blockIdx.x;
    const int rg = threadIdx.x >> 6, lane = threadIdx.x & 63;
    const int c = lane & 15, q = lane >> 4;
    bf16x8 afr[32];
    const float* ap = obs + ((size_t)(rg * 16 + c) * T_ + t) * OBS_;
#pragma unroll
    for (int kb = 0; kb < 32; ++kb) afr[kb] = cvt8(ap + kb * 32 + q * 8);
    for (int jt = 0; jt < 64; ++jt) {
        f32x4 acc = {0.f, 0.f, 0.f, 0.f};
        const short* wgt = po_w1 + (size_t)(jt * 16 + c) * 2048 + 1024;
#pragma unroll 8
        for (int kb = 0; kb < 32; ++kb) acc = MFMA(afr[kb], ld8(wgt + kb * 32 + q * 8), acc);
        const float bias = po_b1[jt * 16 + c];
#pragma unroll
        for (int e = 0; e < 4; ++e) {
            const int br = rg * 16 + q * 4 + e;
            part[((size_t)t * 64 + br) * 1024 + jt * 16 + c] = f2bf(acc[e] + bias);
        }
    }
}

// Persistent scan: 64 blocks x 256 threads, 3 grid barriers per step.
__global__ __launch_bounds__(256, 1) void rssm_scan(
    const short* __restrict__ act_bf, const unsigned char* __restrict__ resets,
    const short* __restrict__ w_ih, const short* __restrict__ w_hh,
    const float* __restrict__ b_ih, const float* __restrict__ b_hh,
    const short* __restrict__ po_w1, const short* __restrict__ po_w2,
    const float* __restrict__ po_b2, const short* __restrict__ part,
    const float* __restrict__ noise,
    int* flags, short* h_bf, short* z_bf, short* poh,
    float* __restrict__ out_h, float* __restrict__ out_qm,
    float* __restrict__ out_qs, float* __restrict__ out_z) {
    __shared__ __align__(16) float stg[64][20];  // pad 20: breaks 4-way bank conflict
    const int tid = threadIdx.x, bid = blockIdx.x;
    const int rg = tid >> 6, lane = tid & 63, c = lane & 15, q = lane >> 4;
    const int j0 = bid * 16, m0 = rg * 16, arow = m0 + c, n = j0 + c;
    const int srow = tid >> 2, sseg = tid & 3;
    const bf16x8 zv8 = {0, 0, 0, 0, 0, 0, 0, 0};

    // init recurrent buffers (ws poisoned 0xAA every launch)
    {
        unsigned long long* hq = (unsigned long long*)h_bf;
        const int idx = bid * 256 + tid;  // 0..16383
        sta8((short*)(hq + idx), 0ull);
        sta8((short*)(hq + idx + 16384), 0ull);
        if (idx < 2048) sta8((short*)((unsigned long long*)z_bf + idx), 0ull);
    }
    int ep = 1;
    gridbar(flags, ep++);

    // loop-invariant prep
    const bool rsA = resets[arow] != 0;
    bool rsR[4];
#pragma unroll
    for (int e = 0; e < 4; ++e) rsR[e] = resets[m0 + q * 4 + e] != 0;
    const short* wiR = w_ih + (size_t)n * 160;
    const short* wiU = w_ih + (size_t)(1024 + n) * 160;
    const short* wiN = w_ih + (size_t)(2048 + n) * 160;
    const short* whR = w_hh + (size_t)n * 1024;
    const short* whU = w_hh + (size_t)(1024 + n) * 1024;
    const short* whN = w_hh + (size_t)(2048 + n) * 1024;
    const float biR = b_ih[n], bhR = b_hh[n];
    const float biU = b_ih[1024 + n], bhU = b_hh[1024 + n];
    const float biN = b_ih[2048 + n], bhN = b_hh[2048 + n];
    const short* w1h = po_w1 + (size_t)n * 2048;
    const int s2 = (bid < 8) ? bid * 16 + c : 0;
    const short* wm = po_w2 + (size_t)s2 * 1024;
    const short* ws2 = po_w2 + (size_t)(128 + s2) * 1024;
    const float bM = (bid < 8) ? po_b2[s2] : 0.f;
    const float bS = (bid < 8) ? po_b2[128 + s2] : 0.f;
    f32x4 hp = {0.f, 0.f, 0.f, 0.f};  // fp32 h carry lives in registers

    for (int t = 0; t < T_; ++t) {
        const int rd = t & 1, wr = rd ^ 1;
        // ---------- phase H: h_t = GRU(h_{t-1}, [z_{t-1}, a_{t-1}]) ----------
        {
            f32x4 aR = {0.f, 0.f, 0.f, 0.f};
            f32x4 aU = aR, aIN = aR, aHN = aR;
            const bool mz = (t > 0) && rsA;
            const short* za = z_bf + arow * 128;
#pragma unroll
            for (int kb = 0; kb < 4; ++kb) {
                const int k = kb * 32 + q * 8;
                bf16x8 a = mz ? zv8 : lda8(za + k);
                aR = MFMA(a, ld8(wiR + k), aR);
                aU = MFMA(a, ld8(wiU + k), aU);
                aIN = MFMA(a, ld8(wiN + k), aIN);
            }
            if (t > 0) {
                const int k = q * 8;
                bf16x8 a = ld8(act_bf + (size_t)arow * (T_ * ACT_) + (size_t)(t - 1) * ACT_ + k);
                aR = MFMA(a, ld8(wiR + 128 + k), aR);
                aU = MFMA(a, ld8(wiU + 128 + k), aU);
                aIN = MFMA(a, ld8(wiN + 128 + k), aIN);
            }
            const short* ha = h_bf + rd * 65536 + arow * 1024;
#pragma unroll 8
            for (int kb = 0; kb < 32; ++kb) {
                const int k = kb * 32 + q * 8;
                bf16x8 a = mz ? zv8 : lda8(ha + k);
                aR = MFMA(a, ld8(whR + k), aR);
                aU = MFMA(a, ld8(whU + k), aU);
                aHN = MFMA(a, ld8(whN + k), aHN);
            }
#pragma unroll
            for (int e = 0; e < 4; ++e) {
                const float keep = (t > 0 && rsR[e]) ? 0.f : 1.f;
                const float hpv = hp[e] * keep;
                const float r = sigm(aR[e] + biR + bhR);
                const float u = sigm(aU[e] + biU + bhU);
                const float nn = tanh_f(aIN[e] + biN + r * (aHN[e] + bhN));
                const float hv = (1.f - u) * nn + u * hpv;
                hp[e] = hv;
                stg[m0 + q * 4 + e][c] = hv;
            }
        }
        __syncthreads();
        {
            float4 hv4 = *(const float4*)&stg[srow][sseg * 4];
            sta8(h_bf + wr * 65536 + srow * 1024 + j0 + sseg * 4, pk4(hv4));
            *(float4*)(out_h + (size_t)srow * (T_ * H_) + (size_t)t * H_ + j0 + sseg * 4) = hv4;
        }
        gridbar(flags, ep++);
        // ---------- phase P1: poh = relu(h @ w1h^T + obs_part) ----------
        {
            f32x4 acc;
#pragma unroll
            for (int e = 0; e < 4; ++e)
                acc[e] = bf2f(part[((size_t)t * 64 + m0 + q * 4 + e) * 1024 + n]);
            const short* ha = h_bf + wr * 65536 + arow * 1024;
#pragma unroll 8
            for (int kb = 0; kb < 32; ++kb) {
                const int k = kb * 32 + q * 8;
                acc = MFMA(lda8(ha + k), ld8(w1h + k), acc);
            }
#pragma unroll
            for (int e = 0; e < 4; ++e) stg[m0 + q * 4 + e][c] = fmaxf(acc[e], 0.f);
        }
        __syncthreads();
        {
            float4 v4 = *(const float4*)&stg[srow][sseg * 4];
            sta8(poh + srow * 1024 + j0 + sseg * 4, pk4(v4));
        }
        gridbar(flags, ep++);
        // ---------- phase P2: qm/qs/z (blocks 0..7) ----------
        if (bid < 8) {
            f32x4 aM = {0.f, 0.f, 0.f, 0.f};
            f32x4 aS = aM;
            const short* pa = poh + arow * 1024;
#pragma unroll 8
            for (int kb = 0; kb < 32; ++kb) {
                const int k = kb * 32 + q * 8;
                bf16x8 a = lda8(pa + k);
                aM = MFMA(a, ld8(wm + k), aM);
                aS = MFMA(a, ld8(ws2 + k), aS);
            }
#pragma unroll
            for (int e = 0; e < 4; ++e) {
                const int row = m0 + q * 4 + e;
                const float qm = aM[e] + bM;
                const float qs = splus(aS[e] + bS) + 1e-6f;
                const float nv = noise[(size_t)row * (T_ * S_) + (size_t)t * S_ + s2];
                stg[row][c] = qm + qs * nv;
                out_qm[(size_t)row * (S_ * T_) + (size_t)s2 * T_ + t] = qm;
                out_qs[(size_t)row * (S_ * T_) + (size_t)s2 * T_ + t] = qs;
            }
            __syncthreads();
            {
                float4 z4 = *(const float4*)&stg[srow][sseg * 4];
                *(float4*)(out_z + (size_t)srow * (T_ * S_) + (size_t)t * S_ + bid * 16 + sseg * 4) = z4;
                sta8(z_bf + srow * 128 + bid * 16 + sseg * 4, pk4(z4));
            }
        }
        gridbar(flags, ep++);
    }
}

// Batched prior MLP over all B*T rows (off critical path)
__global__ __launch_bounds__(256) void prior_mlp(
    const float* __restrict__ hseq, const short* __restrict__ pr_w1,
    const float* __restrict__ pr_b1, const short* __restrict__ pr_w2,
    const float* __restrict__ pr_b2, float* __restrict__ out_pm,
    float* __restrict__ out_ps) {
    __shared__ __align__(16) short hid[64][512];
    const int w = threadIdx.x >> 6;
    const int lane = threadIdx.x & 63;
    const int c = lane & 15, q = lane >> 4;
    const long rb0 = (long)blockIdx.x * 64;
    bf16x8 afr[32];
    const float* ap = hseq + (rb0 + w * 16 + c) * 1024;
#pragma unroll
    for (int kb = 0; kb < 32; ++kb) afr[kb] = cvt8(ap + kb * 32 + q * 8);
    for (int jt = 0; jt < 32; ++jt) {
        f32x4 acc = {0.f, 0.f, 0.f, 0.f};
        const short* wgt = pr_w1 + (size_t)(jt * 16 + c) * 1024;
#pragma unroll 8
        for (int kb = 0; kb < 32; ++kb) acc = MFMA(afr[kb], ld8(wgt + kb * 32 + q * 8), acc);
        const float bias = pr_b1[jt * 16 + c];
#pragma unroll
        for (int e = 0; e < 4; ++e)
            hid[w * 16 + q * 4 + e][jt * 16 + c] = f2bf(fmaxf(acc[e] + bias, 0.f));
    }
    __syncthreads();
    bf16x8 afr2[16];
#pragma unroll
    for (int kb = 0; kb < 16; ++kb) afr2[kb] = *(const bf16x8*)(&hid[w * 16 + c][kb * 32 + q * 8]);
    for (int jt = 0; jt < 16; ++jt) {
        f32x4 acc = {0.f, 0.f, 0.f, 0.f};
        const short* wgt = pr_w2 + (size_t)(jt * 16 + c) * 512;
#pragma unroll 8
        for (int kb = 0; kb < 16; ++kb) acc = MFMA(afr2[kb], ld8(wgt + kb * 32 + q * 8), acc);
        const int col = jt * 16 + c;
#pragma unroll
        for (int e = 0; e < 4; ++e) {
            const long rgidx = rb0 + w * 16 + q * 4 + e;
            const int b_ = (int)(rgidx >> 8), t_ = (int)(rgidx & 255);
            if (col < S_) {
                out_pm[(size_t)b_ * (S_ * T_) + (size_t)col * T_ + t_] = acc[e] + pr_b2[col];
            } else {
                out_ps[(size_t)b_ * (S_ * T_) + (size_t)(col - S_) * T_ + t_] =
                    splus(acc[e] + pr_b2[col]) + 1e-6f;
            }
        }
    }
}

extern "C" void kernel_launch(void* const* d_in, const int* in_sizes, int n_in,
                              void* d_out, int out_size, void* d_ws, size_t ws_size,
                              hipStream_t stream) {
    const float* obs = (const float*)d_in[0];
    const float* action = (const float*)d_in[1];
    const unsigned char* resets = (const unsigned char*)d_in[2];
    const float* noise = (const float*)d_in[3];
    const float* w_ih = (const float*)d_in[4];
    const float* w_hh = (const float*)d_in[5];
    const float* b_ih = (const float*)d_in[6];
    const float* b_hh = (const float*)d_in[7];
    const float* pr_w1 = (const float*)d_in[8];
    const float* pr_b1 = (const float*)d_in[9];
    const float* pr_w2 = (const float*)d_in[10];
    const float* pr_b2 = (const float*)d_in[11];
    const float* po_w1 = (const float*)d_in[12];
    const float* po_b1 = (const float*)d_in[13];
    const float* po_w2 = (const float*)d_in[14];
    const float* po_b2 = (const float*)d_in[15];

    float* out = (float*)d_out;
    const size_t BST = (size_t)B_ * S_ * T_;  // 2097152
    float* out_pm = out;
    float* out_ps = out + BST;
    float* out_qm = out + 2 * BST;
    float* out_qs = out + 3 * BST;
    float* out_h = out + 4 * BST;
    float* out_z = out + 4 * BST + (size_t)B_ * T_ * H_;

    char* w = (char*)d_ws;
    int* flags = (int*)w;                      // 4096 B (64 x 64B)
    short* h_bf = (short*)(w + 4096);          // 2 x 64x1024
    short* z_bf = (short*)(w + 266240);        // 64x128
    short* poh = (short*)(w + 282624);         // 64x1024
    short* act_bf = (short*)(w + 413696);      // 64x256x32
    short* w_ih_bf = (short*)(w + 1462272);    // 3072x160
    short* w_hh_bf = (short*)(w + 2445312);    // 3072x1024
    short* po_w1_bf = (short*)(w + 8736768);   // 1024x2048
    short* po_w2_bf = (short*)(w + 12931072);  // 256x1024
    short* pr_w1_bf = (short*)(w + 13455360);  // 512x1024
    short* pr_w2_bf = (short*)(w + 14503936);  // 256x512
    short* part = (short*)(w + 14766080);      // [T][64][1024] bf16 = 32 MB

    auto cvt = [&](const float* s, short* d, int n) {
        int n4 = n / 4;
        f2bf_arr<<<dim3((n4 + 255) / 256), 256, 0, stream>>>(s, d, n4);
    };
    cvt(action, act_bf, B_ * T_ * ACT_);
    cvt(w_ih, w_ih_bf, 3 * H_ * (S_ + ACT_));
    cvt(w_hh, w_hh_bf, 3 * H_ * H_);
    cvt(po_w1, po_w1_bf, 1024 * 2048);
    cvt(po_w2, po_w2_bf, 256 * 1024);
    cvt(pr_w1, pr_w1_bf, 512 * 1024);
    cvt(pr_w2, pr_w2_bf, 256 * 512);

    obs_gemm<<<dim3(256), 256, 0, stream>>>(obs, po_w1_bf, po_b1, part);

    rssm_scan<<<dim3(64), 256, 0, stream>>>(
        act_bf, resets, w_ih_bf, w_hh_bf, b_ih, b_hh,
        po_w1_bf, po_w2_bf, po_b2, part, noise,
        flags, h_bf, z_bf, poh, out_h, out_qm, out_qs, out_z);

    prior_mlp<<<dim3(256), 256, 0, stream>>>(out_h, pr_w1_bf, pr_b1, pr_w2_bf, pr_b2,
                                             out_pm, out_ps);
}